// Round 11
// baseline (213.386 us; speedup 1.0000x reference)
//
#include <hip/hip_runtime.h>
#include <hip/hip_cooperative_groups.h>

namespace cg = cooperative_groups;

// GraphSAGE 2-layer inference. N=40000, E=640000, C=128, OUT=121.
// R11: R10's cooperative mega-kernel, but the grid is sized from the
// hardware occupancy query (R10 hard-coded 1024 and the coop launch was
// rejected -> output zeros). If the coop path is unavailable, fall back to
// the same phases as 6 plain dispatches (== proven R9 structure).
// Phases: [zero||x->bf16||prepack] -> bucket(XCC-local atomics) ->
// agg1 -> gemm1 -> agg2 -> gemm2, all grid-strided.

#define NCH 128
#define CAPX 16  // per-XCD slots per node
#define EPT 8    // edges per thread in bucket phase

typedef __bf16 bf16x8 __attribute__((ext_vector_type(8)));
typedef float f32x4 __attribute__((ext_vector_type(4)));
typedef unsigned short ushort8 __attribute__((ext_vector_type(8)));

static __device__ __forceinline__ unsigned short f2b(float f) {
  return __builtin_bit_cast(unsigned short, static_cast<__bf16>(f));
}
static __device__ __forceinline__ float b2f(unsigned short u) {
  union { unsigned int i; float f; } v;
  v.i = ((unsigned int)u) << 16;
  return v.f;
}

struct Params {
  const int* src; const int* dst; int E;
  int* cntx; unsigned short* slotu; int* ovf_n; int2* ovf;
  const float* x; unsigned short* xb; int n4;
  const float* W1l; const float* W1r; const float* b1l; const float* b1r;
  const float* W2l; const float* W2r; const float* b2l; const float* b2r;
  unsigned short* pack1; unsigned short* pack2;
  float* bsum1; float* bsum2;
  unsigned short* aggb; unsigned short* hb;
  float* out;
  int N; int NOUT;
};

// ---- P0: zero cntx/ovf_n || x->bf16 || weight prepack (grid-strided) ----
__device__ __forceinline__ void phase_setup(const Params& p) {
  const int gthreads = gridDim.x * 256;
  const int gtid = blockIdx.x * 256 + (int)threadIdx.x;
  const int nz4 = p.N * 2;  // N*8 ints as int4
  const int4 z = {0, 0, 0, 0};
  for (int i = gtid; i < nz4; i += gthreads) ((int4*)p.cntx)[i] = z;
  if (gtid == 0) *p.ovf_n = 0;
  for (int i = gtid; i < p.n4; i += gthreads) {
    float4 v = ((const float4*)p.x)[i];
    ushort4 r;
    r.x = f2b(v.x); r.y = f2b(v.y); r.z = f2b(v.z); r.w = f2b(v.w);
    ((ushort4*)p.xb)[i] = r;
  }
  // prepack: pack[c][t][lane][j] = W'[c*32+(lane>>4)*8+j][t*16+(lane&15)]
  for (int vt = gtid; vt < 8192; vt += gthreads) {
    const int layer = vt >> 12;
    const int tid2 = vt & 4095;
    const float* Wl = layer ? p.W2l : p.W1l;
    const float* Wr = layer ? p.W2r : p.W1r;
    const float* bl = layer ? p.b2l : p.b1l;
    const float* br = layer ? p.b2r : p.b1r;
    unsigned short* pack = layer ? p.pack2 : p.pack1;
    float* bsum = layer ? p.bsum2 : p.bsum1;
    const int NO = layer ? p.NOUT : NCH;
    const int c = tid2 >> 9;
    const int t = (tid2 >> 6) & 7;
    const int l = tid2 & 63;
    const int n = t * 16 + (l & 15);
    const int kb = c * 32 + ((l >> 4) << 3);
    unsigned short o[8];
#pragma unroll
    for (int j = 0; j < 8; ++j) {
      const int k = kb + j;
      float v = 0.f;
      if (n < NO) v = (k < 128) ? Wl[n * 128 + k] : Wr[n * 128 + (k - 128)];
      o[j] = f2b(v);
    }
    ushort4 lo, hi;
    lo.x = o[0]; lo.y = o[1]; lo.z = o[2]; lo.w = o[3];
    hi.x = o[4]; hi.y = o[5]; hi.z = o[6]; hi.w = o[7];
    *(ushort4*)(pack + (long)tid2 * 8) = lo;
    *(ushort4*)(pack + (long)tid2 * 8 + 4) = hi;
    if (tid2 < 128) bsum[tid2] = (tid2 < NO) ? (bl[tid2] + br[tid2]) : 0.f;
  }
}

// ---- P1: bucket build (XCC-local atomics, 8 edges/thread) ----
__device__ __forceinline__ void phase_bucket(const Params& p) {
  unsigned int xcc;
  asm volatile("s_getreg_b32 %0, hwreg(HW_REG_XCC_ID)" : "=s"(xcc));
  xcc &= 7u;
  const int nbBkt = (p.E + 256 * EPT - 1) / (256 * EPT);
  for (int blk = blockIdx.x; blk < nbBkt; blk += gridDim.x) {
    const int base = blk * (256 * EPT) + (int)threadIdx.x;
    int d[EPT], s[EPT], pos[EPT];
#pragma unroll
    for (int j = 0; j < EPT; ++j) {
      const int e = base + j * 256;
      const bool ok = e < p.E;
      d[j] = ok ? p.dst[e] : -1;
      s[j] = ok ? p.src[e] : 0;
    }
#pragma unroll
    for (int j = 0; j < EPT; ++j) {
      pos[j] = (d[j] >= 0)
          ? __hip_atomic_fetch_add(&p.cntx[(long)d[j] * 8 + xcc], 1,
                                   __ATOMIC_RELAXED, __HIP_MEMORY_SCOPE_WORKGROUP)
          : 0;
    }
#pragma unroll
    for (int j = 0; j < EPT; ++j) {
      if (d[j] >= 0) {
        if (pos[j] < CAPX)
          p.slotu[(long)d[j] * 128 + xcc * CAPX + pos[j]] = (unsigned short)s[j];
        else {
          int o = atomicAdd(p.ovf_n, 1);  // device-scope, ~never taken
          p.ovf[o] = make_int2(d[j], s[j]);
        }
      }
    }
  }
}

// ---- agg phase: 16 nodes/block, compact slots to LDS, 8-deep gather ----
__device__ __forceinline__ void phase_agg(
    const unsigned short* __restrict__ feat, const int* __restrict__ cntx,
    const unsigned short* __restrict__ slotu, const int* __restrict__ ovf_n,
    const int2* __restrict__ ovf, unsigned short* __restrict__ agg, int N,
    unsigned short (*list)[128], int* degs, int* ms) {
  const int lg = threadIdx.x >> 4;
  const int ln = threadIdx.x & 15;
  const int nblk = (N + 15) / 16;
  for (int gb = blockIdx.x; gb < nblk; gb += gridDim.x) {
    const int g = gb * 16 + lg;
    __syncthreads();  // protect list[] reuse across grid-stride iterations
    if (g < N) {
      const int4 cA = *(const int4*)(cntx + (long)g * 8);
      const int4 cB = *(const int4*)(cntx + (long)g * 8 + 4);
      const int c[8] = {cA.x, cA.y, cA.z, cA.w, cB.x, cB.y, cB.z, cB.w};
      int deg = 0, pp = 0, myoff = 0, mycc = 0;
#pragma unroll
      for (int xx = 0; xx < 8; ++xx) {
        const int cc = (c[xx] < CAPX) ? c[xx] : CAPX;
        if (ln == xx) { myoff = pp; mycc = cc; }
        pp += cc;
        deg += c[xx];
      }
      if (ln == 0) { degs[lg] = deg; ms[lg] = pp; }
      if (ln < 8 && mycc > 0) {
        const unsigned short* sp = slotu + (long)g * 128 + ln * CAPX;
        for (int i = 0; i < mycc; ++i) list[lg][myoff + i] = sp[i];
      }
    } else if (ln == 0) {
      degs[lg] = 0; ms[lg] = 0;
    }
    __syncthreads();

    if (g < N) {
      const int m = ms[lg];
      const int col = ln * 8;
      const unsigned short* fcol = feat + col;
      float acc[8];
#pragma unroll
      for (int k = 0; k < 8; ++k) acc[k] = 0.f;
      const unsigned short* __restrict__ il = list[lg];
      int j = 0;
      for (; j + 7 < m; j += 8) {
        const int i0 = il[j + 0], i1 = il[j + 1], i2 = il[j + 2], i3 = il[j + 3];
        const int i4 = il[j + 4], i5 = il[j + 5], i6 = il[j + 6], i7 = il[j + 7];
        const ushort8 v0 = *(const ushort8*)(fcol + (long)i0 * NCH);
        const ushort8 v1 = *(const ushort8*)(fcol + (long)i1 * NCH);
        const ushort8 v2 = *(const ushort8*)(fcol + (long)i2 * NCH);
        const ushort8 v3 = *(const ushort8*)(fcol + (long)i3 * NCH);
        const ushort8 v4 = *(const ushort8*)(fcol + (long)i4 * NCH);
        const ushort8 v5 = *(const ushort8*)(fcol + (long)i5 * NCH);
        const ushort8 v6 = *(const ushort8*)(fcol + (long)i6 * NCH);
        const ushort8 v7 = *(const ushort8*)(fcol + (long)i7 * NCH);
#pragma unroll
        for (int k = 0; k < 8; ++k) {
          acc[k] += b2f(v0[k]); acc[k] += b2f(v1[k]);
          acc[k] += b2f(v2[k]); acc[k] += b2f(v3[k]);
          acc[k] += b2f(v4[k]); acc[k] += b2f(v5[k]);
          acc[k] += b2f(v6[k]); acc[k] += b2f(v7[k]);
        }
      }
      if (j + 3 < m) {
        const int i0 = il[j + 0], i1 = il[j + 1], i2 = il[j + 2], i3 = il[j + 3];
        const ushort8 v0 = *(const ushort8*)(fcol + (long)i0 * NCH);
        const ushort8 v1 = *(const ushort8*)(fcol + (long)i1 * NCH);
        const ushort8 v2 = *(const ushort8*)(fcol + (long)i2 * NCH);
        const ushort8 v3 = *(const ushort8*)(fcol + (long)i3 * NCH);
#pragma unroll
        for (int k = 0; k < 8; ++k) {
          acc[k] += b2f(v0[k]); acc[k] += b2f(v1[k]);
          acc[k] += b2f(v2[k]); acc[k] += b2f(v3[k]);
        }
        j += 4;
      }
      for (; j < m; ++j) {
        const ushort8 v = *(const ushort8*)(fcol + (long)il[j] * NCH);
#pragma unroll
        for (int k = 0; k < 8; ++k) acc[k] += b2f(v[k]);
      }
      const int on = *ovf_n;  // normally 0
      for (int o = 0; o < on; ++o) {
        const int2 pr = ovf[o];
        if (pr.x == g) {
          const ushort8 v = *(const ushort8*)(fcol + (long)pr.y * NCH);
#pragma unroll
          for (int k = 0; k < 8; ++k) acc[k] += b2f(v[k]);
        }
      }
      const int deg = degs[lg];
      const int dd = (deg < 1) ? 1 : deg;
      const float inv = 1.f / (float)dd;
      ushort8 r;
#pragma unroll
      for (int k = 0; k < 8; ++k) r[k] = f2b(acc[k] * inv);
      *(ushort8*)(agg + (long)g * NCH + col) = r;
    }
  }
}

// ---- MFMA dual-GEMM phase (grid-strided over 128-row tiles) ----
__device__ __forceinline__ void phase_gemm(
    const unsigned short* __restrict__ Ag, const unsigned short* __restrict__ Sf,
    const unsigned short* __restrict__ pack, const float* __restrict__ bsum,
    unsigned short* __restrict__ outb, float* __restrict__ outf,
    int M, int NO, int do_relu) {
  const int wave = threadIdx.x >> 6;
  const int lane = threadIdx.x & 63;
  const int mrow = lane & 15;
  const int koct = (lane >> 4) * 8;
  const int nloc = lane & 15;
  const int rquad = (lane >> 4) * 4;
  const int ntile = (M + 127) / 128;

  for (int tile = blockIdx.x; tile < ntile; tile += gridDim.x) {
    const int R = tile * 128 + wave * 32;
    int r0 = R + mrow;       if (r0 > M - 1) r0 = M - 1;
    int r1 = R + 16 + mrow;  if (r1 > M - 1) r1 = M - 1;

    f32x4 acc[2][8];
#pragma unroll
    for (int mt = 0; mt < 2; ++mt)
#pragma unroll
      for (int t = 0; t < 8; ++t) acc[mt][t] = (f32x4){0.f, 0.f, 0.f, 0.f};

#pragma unroll
    for (int c = 0; c < 8; ++c) {
      const unsigned short* __restrict__ Abase = (c < 4) ? Ag : Sf;
      const int k0 = (c & 3) * 32;
      const bf16x8 a0 = *(const bf16x8*)(Abase + (long)r0 * NCH + k0 + koct);
      const bf16x8 a1 = *(const bf16x8*)(Abase + (long)r1 * NCH + k0 + koct);
      const unsigned short* bp = pack + ((long)(c * 8) * 64 + lane) * 8;
#pragma unroll
      for (int t = 0; t < 8; ++t) {
        const bf16x8 bfrag = *(const bf16x8*)(bp + (long)t * 512);
        acc[0][t] = __builtin_amdgcn_mfma_f32_16x16x32_bf16(a0, bfrag, acc[0][t], 0, 0, 0);
        acc[1][t] = __builtin_amdgcn_mfma_f32_16x16x32_bf16(a1, bfrag, acc[1][t], 0, 0, 0);
      }
    }

#pragma unroll
    for (int mt = 0; mt < 2; ++mt) {
#pragma unroll
      for (int t = 0; t < 8; ++t) {
        const int n = t * 16 + nloc;
        const float bias = bsum[n];
#pragma unroll
        for (int r = 0; r < 4; ++r) {
          const int m = R + mt * 16 + rquad + r;
          if (m < M && n < NO) {
            float v = acc[mt][t][r] + bias;
            if (do_relu) v = fmaxf(v, 0.f);
            if (outb) outb[(long)m * NCH + n] = f2b(v);
            else outf[(long)m * NO + n] = v;
          }
        }
      }
    }
  }
}

// ---- single cooperative kernel ----
__global__ __launch_bounds__(256) void k_all(Params p) {
  cg::grid_group grid = cg::this_grid();
  __shared__ unsigned short list[16][128];
  __shared__ int degs[16], ms[16];

  phase_setup(p);
  grid.sync();
  phase_bucket(p);
  grid.sync();
  phase_agg(p.xb, p.cntx, p.slotu, p.ovf_n, p.ovf, p.aggb, p.N, list, degs, ms);
  grid.sync();
  phase_gemm(p.aggb, p.xb, p.pack1, p.bsum1, p.hb, (float*)nullptr, p.N, NCH, 1);
  grid.sync();
  phase_agg(p.hb, p.cntx, p.slotu, p.ovf_n, p.ovf, p.aggb, p.N, list, degs, ms);
  grid.sync();
  phase_gemm(p.aggb, p.hb, p.pack2, p.bsum2, (unsigned short*)nullptr, p.out,
             p.N, p.NOUT, 0);
}

// ---- fallback wrappers (plain dispatches, R9-equivalent) ----
__global__ __launch_bounds__(256) void k_p_setup(Params p) { phase_setup(p); }
__global__ __launch_bounds__(256) void k_p_bucket(Params p) { phase_bucket(p); }
__global__ __launch_bounds__(256) void k_p_agg(Params p, const unsigned short* feat) {
  __shared__ unsigned short list[16][128];
  __shared__ int degs[16], ms[16];
  phase_agg(feat, p.cntx, p.slotu, p.ovf_n, p.ovf, p.aggb, p.N, list, degs, ms);
}
__global__ __launch_bounds__(256) void k_p_gemm(
    const unsigned short* Ag, const unsigned short* Sf,
    const unsigned short* pack, const float* bsum,
    unsigned short* outb, float* outf, int M, int NO, int do_relu) {
  phase_gemm(Ag, Sf, pack, bsum, outb, outf, M, NO, do_relu);
}

// ---------------- launch ----------------

extern "C" void kernel_launch(void* const* d_in, const int* in_sizes, int n_in,
                              void* d_out, int out_size, void* d_ws, size_t ws_size,
                              hipStream_t stream) {
  const int N = in_sizes[0] / NCH;  // 40000
  const int E = in_sizes[1] / 2;    // 640000
  const int NOUT = out_size / N;    // 121

  char* w = (char*)d_ws;
  auto alloc = [&](size_t bytes) {
    char* p = w;
    w += (bytes + 255) & ~(size_t)255;
    return p;
  };
  unsigned short* xb = (unsigned short*)alloc((size_t)N * NCH * 2);
  unsigned short* hb = (unsigned short*)alloc((size_t)N * NCH * 2);
  unsigned short* aggb = (unsigned short*)alloc((size_t)N * NCH * 2);
  unsigned short* pack1 = (unsigned short*)alloc(8 * 8 * 64 * 8 * 2);
  unsigned short* pack2 = (unsigned short*)alloc(8 * 8 * 64 * 8 * 2);
  float* bsum1 = (float*)alloc(128 * 4);
  float* bsum2 = (float*)alloc(128 * 4);
  int* cntx = (int*)alloc(((size_t)N * 8 + 4) * 4);  // [node][xcc] + ovf_n
  int* ovf_n = cntx + (size_t)N * 8;
  unsigned short* slotu = (unsigned short*)alloc((size_t)N * 128 * 2);
  int2* ovf = (int2*)alloc((size_t)E * 8);

  Params p;
  p.src = (const int*)d_in[1];
  p.dst = ((const int*)d_in[1]) + E;
  p.E = E;
  p.cntx = cntx; p.slotu = slotu; p.ovf_n = ovf_n; p.ovf = ovf;
  p.x = (const float*)d_in[0]; p.xb = xb; p.n4 = N * NCH / 4;
  p.W1l = (const float*)d_in[2]; p.b1l = (const float*)d_in[3];
  p.W1r = (const float*)d_in[4]; p.b1r = (const float*)d_in[5];
  p.W2l = (const float*)d_in[6]; p.b2l = (const float*)d_in[7];
  p.W2r = (const float*)d_in[8]; p.b2r = (const float*)d_in[9];
  p.pack1 = pack1; p.pack2 = pack2; p.bsum1 = bsum1; p.bsum2 = bsum2;
  p.aggb = aggb; p.hb = hb;
  p.out = (float*)d_out;
  p.N = N; p.NOUT = NOUT;

  // size the cooperative grid from what the HW will actually co-schedule
  int dev = 0;
  hipGetDevice(&dev);
  int ncu = 0;
  hipDeviceGetAttribute(&ncu, hipDeviceAttributeMultiprocessorCount, dev);
  int occ = 0;
  hipOccupancyMaxActiveBlocksPerMultiprocessor(&occ, k_all, 256, 0);

  bool launched = false;
  if (occ > 0 && ncu > 0) {
    int grid = occ * ncu;
    if (grid > 1024) grid = 1024;
    void* args[] = {&p};
    hipError_t err = hipLaunchCooperativeKernel((const void*)k_all, dim3(grid),
                                                dim3(256), args, 0, stream);
    launched = (err == hipSuccess);
  }

  if (!launched) {  // fallback: same phases, 6 plain dispatches
    const int gagg = (N + 15) / 16;   // 2500
    const int gtile = (N + 127) / 128;  // 313
    const int gbkt = (E + 256 * EPT - 1) / (256 * EPT);  // 313
    k_p_setup<<<1024, 256, 0, stream>>>(p);
    k_p_bucket<<<gbkt, 256, 0, stream>>>(p);
    k_p_agg<<<gagg, 256, 0, stream>>>(p, xb);
    k_p_gemm<<<gtile, 256, 0, stream>>>(aggb, xb, pack1, bsum1, hb,
                                        (float*)nullptr, N, NCH, 1);
    k_p_agg<<<gagg, 256, 0, stream>>>(p, hb);
    k_p_gemm<<<gtile, 256, 0, stream>>>(aggb, hb, pack2, bsum2,
                                        (unsigned short*)nullptr, (float*)d_out,
                                        N, NOUT, 0);
  }
}

// Round 12
// 200.897 us; speedup vs baseline: 1.0622x; 1.0622x over previous
//
#include <hip/hip_runtime.h>
#include <hip/hip_fp8.h>

// GraphSAGE 2-layer inference. N=40000, E=640000, C=128, OUT=121.
// R12 = R9 (proven 6-dispatch shape; coop mega-kernel R10/R11 regressed:
// shared 196-VGPR binary starved the gather phases) + fp8-e4m3 GATHER PATH:
// agg reads fp8 rows (128B = 2 cache lines/edge vs 4), fp32 accumulate,
// bf16 agg out; GEMMs + self path stay bf16. Decode via exact 256-entry
// LDS LUT. k_main emits x8; gemm1 epilogue emits h8.
// 6 dispatches: memset -> k_main(bucket||convert||prepack) -> agg -> gemm -> agg -> gemm.

#define NCH 128
#define CAPX 16  // per-XCD slots per node
#define EPT 8    // edges per thread in bucket phase

typedef __bf16 bf16x8 __attribute__((ext_vector_type(8)));
typedef float f32x4 __attribute__((ext_vector_type(4)));
typedef unsigned char uchar8 __attribute__((ext_vector_type(8)));

static __device__ __forceinline__ unsigned short f2b(float f) {
  return __builtin_bit_cast(unsigned short, static_cast<__bf16>(f));
}
static __device__ __forceinline__ unsigned char f2q(float f) {
  __hip_fp8_e4m3 q(f);
  return (unsigned char)q.__x;
}
static __device__ __forceinline__ float q2f(unsigned char b) {
  __hip_fp8_e4m3 q;
  q.__x = (__hip_fp8_storage_t)b;
  return (float)q;
}

// ---------------- fused main: bucket CSR || x->bf16+fp8 || weight prepack ----------------
// pack[c][t][lane][j] = W'[c*32 + (lane>>4)*8 + j][t*16 + (lane&15)]
// (B-frag for mfma_f32_16x16x32_bf16: n=lane&15, k=(lane>>4)*8+j); W' = [Wl;Wr].
__global__ __launch_bounds__(256) void k_main(
    const int* __restrict__ src, const int* __restrict__ dst, int E,
    int* __restrict__ cntx, unsigned short* __restrict__ slotu,
    int* __restrict__ ovf_n, int2* __restrict__ ovf,
    const float* __restrict__ x, unsigned short* __restrict__ xb,
    unsigned char* __restrict__ x8, int n4,
    const float* __restrict__ W1l, const float* __restrict__ W1r,
    const float* __restrict__ b1l, const float* __restrict__ b1r,
    const float* __restrict__ W2l, const float* __restrict__ W2r,
    const float* __restrict__ b2l, const float* __restrict__ b2r,
    unsigned short* __restrict__ pack1, unsigned short* __restrict__ pack2,
    float* __restrict__ bsum1, float* __restrict__ bsum2, int NOUT,
    int nbBkt, int nbCvt) {
  int blk = blockIdx.x;
  if (blk < nbBkt) {  // bucket: 8 edges/thread, XCC-local atomics (R9)
    unsigned int xcc;
    asm volatile("s_getreg_b32 %0, hwreg(HW_REG_XCC_ID)" : "=s"(xcc));
    xcc &= 7u;
    const int base = blk * (256 * EPT) + (int)threadIdx.x;
    int d[EPT], s[EPT], pos[EPT];
#pragma unroll
    for (int j = 0; j < EPT; ++j) {
      const int e = base + j * 256;
      const bool ok = e < E;
      d[j] = ok ? dst[e] : -1;
      s[j] = ok ? src[e] : 0;
    }
#pragma unroll
    for (int j = 0; j < EPT; ++j) {
      pos[j] = (d[j] >= 0)
          ? __hip_atomic_fetch_add(&cntx[(long)d[j] * 8 + xcc], 1,
                                   __ATOMIC_RELAXED, __HIP_MEMORY_SCOPE_WORKGROUP)
          : 0;
    }
#pragma unroll
    for (int j = 0; j < EPT; ++j) {
      if (d[j] >= 0) {
        if (pos[j] < CAPX)
          slotu[(long)d[j] * 128 + xcc * CAPX + pos[j]] = (unsigned short)s[j];
        else {
          int o = atomicAdd(ovf_n, 1);  // device-scope, ~never taken
          ovf[o] = make_int2(d[j], s[j]);
        }
      }
    }
    return;
  }
  blk -= nbBkt;
  if (blk < nbCvt) {  // fp32 -> bf16 + fp8 convert
    int i = blk * 256 + threadIdx.x;
    if (i < n4) {
      float4 v = ((const float4*)x)[i];
      ushort4 r;
      r.x = f2b(v.x); r.y = f2b(v.y); r.z = f2b(v.z); r.w = f2b(v.w);
      ((ushort4*)xb)[i] = r;
      uchar4 q;
      q.x = f2q(v.x); q.y = f2q(v.y); q.z = f2q(v.z); q.w = f2q(v.w);
      ((uchar4*)x8)[i] = q;
    }
    return;
  }
  blk -= nbCvt;  // prepack: 32 blocks, 16 per layer
  const int layer = blk >> 4;
  const float* Wl = layer ? W2l : W1l;
  const float* Wr = layer ? W2r : W1r;
  const float* bl = layer ? b2l : b1l;
  const float* br = layer ? b2r : b1r;
  unsigned short* pack = layer ? pack2 : pack1;
  float* bsum = layer ? bsum2 : bsum1;
  const int NO = layer ? NOUT : NCH;
  int tid = (blk & 15) * 256 + threadIdx.x;  // 0..4095
  int c = tid >> 9;
  int t = (tid >> 6) & 7;
  int l = tid & 63;
  int n = t * 16 + (l & 15);
  int kb = c * 32 + ((l >> 4) << 3);
  unsigned short o[8];
#pragma unroll
  for (int j = 0; j < 8; ++j) {
    int k = kb + j;
    float v = 0.f;
    if (n < NO) v = (k < 128) ? Wl[n * 128 + k] : Wr[n * 128 + (k - 128)];
    o[j] = f2b(v);
  }
  ushort4 lo, hi;
  lo.x = o[0]; lo.y = o[1]; lo.z = o[2]; lo.w = o[3];
  hi.x = o[4]; hi.y = o[5]; hi.z = o[6]; hi.w = o[7];
  *(ushort4*)(pack + (long)tid * 8) = lo;
  *(ushort4*)(pack + (long)tid * 8 + 4) = hi;
  if (tid < 128) bsum[tid] = (tid < NO) ? (bl[tid] + br[tid]) : 0.f;
}

// ---------------- mean aggregation (fp8 gather, fp32 accum, bf16 out) ----------------
// Block = 16 groups x 16 lanes; group = one node. Phase A: compact the node's
// per-XCD slots into LDS. Phase B: 8-deep uchar8 (8B) gather from fp8 rows
// (128B/row = 2 lines vs 4 for bf16), decode via exact 256-entry LDS LUT.
__global__ __launch_bounds__(256) void k_agg(
    const unsigned char* __restrict__ feat8, const int* __restrict__ cntx,
    const unsigned short* __restrict__ slotu, const int* __restrict__ ovf_n,
    const int2* __restrict__ ovf, unsigned short* __restrict__ agg, int N) {
  __shared__ unsigned short list[16][128];
  __shared__ float lut[256];
  __shared__ int degs[16], ms[16];
  const int lg = threadIdx.x >> 4;  // group in block
  const int ln = threadIdx.x & 15;  // lane in group
  const int g = blockIdx.x * 16 + lg;

  lut[threadIdx.x] = q2f((unsigned char)threadIdx.x);  // 256 threads = 256 entries

  // ---- phase A: build compact index list ----
  if (g < N) {
    const int4 cA = *(const int4*)(cntx + (long)g * 8);
    const int4 cB = *(const int4*)(cntx + (long)g * 8 + 4);
    const int c[8] = {cA.x, cA.y, cA.z, cA.w, cB.x, cB.y, cB.z, cB.w};
    int deg = 0, p = 0, myoff = 0, mycc = 0;
#pragma unroll
    for (int xx = 0; xx < 8; ++xx) {
      const int cc = (c[xx] < CAPX) ? c[xx] : CAPX;
      if (ln == xx) { myoff = p; mycc = cc; }
      p += cc;
      deg += c[xx];
    }
    if (ln == 0) { degs[lg] = deg; ms[lg] = p; }
    if (ln < 8 && mycc > 0) {
      const unsigned short* sp = slotu + (long)g * 128 + ln * CAPX;
      for (int i = 0; i < mycc; ++i) list[lg][myoff + i] = sp[i];
    }
  } else if (ln == 0) {
    degs[lg] = 0; ms[lg] = 0;
  }
  __syncthreads();

  if (g >= N) return;
  const int m = ms[lg];
  const int col = ln * 8;  // 8 channels per lane
  const unsigned char* fcol = feat8 + col;

  float acc[8];
#pragma unroll
  for (int k = 0; k < 8; ++k) acc[k] = 0.f;

  const unsigned short* __restrict__ il = list[lg];
  int j = 0;
  for (; j + 7 < m; j += 8) {
    const int i0 = il[j + 0], i1 = il[j + 1], i2 = il[j + 2], i3 = il[j + 3];
    const int i4 = il[j + 4], i5 = il[j + 5], i6 = il[j + 6], i7 = il[j + 7];
    const uchar8 v0 = *(const uchar8*)(fcol + (long)i0 * NCH);
    const uchar8 v1 = *(const uchar8*)(fcol + (long)i1 * NCH);
    const uchar8 v2 = *(const uchar8*)(fcol + (long)i2 * NCH);
    const uchar8 v3 = *(const uchar8*)(fcol + (long)i3 * NCH);
    const uchar8 v4 = *(const uchar8*)(fcol + (long)i4 * NCH);
    const uchar8 v5 = *(const uchar8*)(fcol + (long)i5 * NCH);
    const uchar8 v6 = *(const uchar8*)(fcol + (long)i6 * NCH);
    const uchar8 v7 = *(const uchar8*)(fcol + (long)i7 * NCH);
#pragma unroll
    for (int k = 0; k < 8; ++k) {
      acc[k] += lut[v0[k]]; acc[k] += lut[v1[k]];
      acc[k] += lut[v2[k]]; acc[k] += lut[v3[k]];
      acc[k] += lut[v4[k]]; acc[k] += lut[v5[k]];
      acc[k] += lut[v6[k]]; acc[k] += lut[v7[k]];
    }
  }
  if (j + 3 < m) {
    const int i0 = il[j + 0], i1 = il[j + 1], i2 = il[j + 2], i3 = il[j + 3];
    const uchar8 v0 = *(const uchar8*)(fcol + (long)i0 * NCH);
    const uchar8 v1 = *(const uchar8*)(fcol + (long)i1 * NCH);
    const uchar8 v2 = *(const uchar8*)(fcol + (long)i2 * NCH);
    const uchar8 v3 = *(const uchar8*)(fcol + (long)i3 * NCH);
#pragma unroll
    for (int k = 0; k < 8; ++k) {
      acc[k] += lut[v0[k]]; acc[k] += lut[v1[k]];
      acc[k] += lut[v2[k]]; acc[k] += lut[v3[k]];
    }
    j += 4;
  }
  for (; j < m; ++j) {
    const uchar8 v = *(const uchar8*)(fcol + (long)il[j] * NCH);
#pragma unroll
    for (int k = 0; k < 8; ++k) acc[k] += lut[v[k]];
  }

  // overflow pass (normally empty; keeps exactness for any input)
  const int on = *ovf_n;
  for (int o = 0; o < on; ++o) {
    const int2 p = ovf[o];
    if (p.x == g) {
      const uchar8 v = *(const uchar8*)(fcol + (long)p.y * NCH);
#pragma unroll
      for (int k = 0; k < 8; ++k) acc[k] += lut[v[k]];
    }
  }

  const int deg = degs[lg];
  const int dd = (deg < 1) ? 1 : deg;
  const float inv = 1.f / (float)dd;
  ushort4 rlo, rhi;
  rlo.x = f2b(acc[0] * inv); rlo.y = f2b(acc[1] * inv);
  rlo.z = f2b(acc[2] * inv); rlo.w = f2b(acc[3] * inv);
  rhi.x = f2b(acc[4] * inv); rhi.y = f2b(acc[5] * inv);
  rhi.z = f2b(acc[6] * inv); rhi.w = f2b(acc[7] * inv);
  *(ushort4*)(agg + (long)g * NCH + col) = rlo;
  *(ushort4*)(agg + (long)g * NCH + col + 4) = rhi;
}

// ---------------- MFMA dual-GEMM ----------------
// out[m][n] = relu?( sum_k agg[m][k]Wl[n][k] + self[m][k]Wr[n][k] + bias[n] )
// LDS-free: wave = 32 rows x 128 cols; K'=256 in 8 chunks; A-frags from
// global bf16 (16B/lane), B-frags from prepacked weights (L2-hot, 64KB).
// Layer 1 additionally emits h8 (fp8) for the next layer's gather.
__global__ __launch_bounds__(256) void k_gemm(
    const unsigned short* __restrict__ Ag,   // agg  bf16 [M][128]
    const unsigned short* __restrict__ Sf,   // self bf16 [M][128]
    const unsigned short* __restrict__ pack, // [8][8][64][8] bf16
    const float* __restrict__ bsum,          // [128]
    unsigned short* __restrict__ outb,       // bf16 out (layer1) or null
    unsigned char* __restrict__ out8,        // fp8 out (layer1) or null
    float* __restrict__ outf,                // f32 out (layer2) or null
    int M, int NO, int do_relu) {
  const int wave = threadIdx.x >> 6;
  const int lane = threadIdx.x & 63;
  const int R = blockIdx.x * 128 + wave * 32;  // 2 m-tiles: R, R+16
  const int mrow = lane & 15;
  const int koct = (lane >> 4) * 8;

  int r0 = R + mrow;       if (r0 > M - 1) r0 = M - 1;
  int r1 = R + 16 + mrow;  if (r1 > M - 1) r1 = M - 1;

  f32x4 acc[2][8];
#pragma unroll
  for (int mt = 0; mt < 2; ++mt)
#pragma unroll
    for (int t = 0; t < 8; ++t) acc[mt][t] = (f32x4){0.f, 0.f, 0.f, 0.f};

#pragma unroll
  for (int c = 0; c < 8; ++c) {
    const unsigned short* __restrict__ Abase = (c < 4) ? Ag : Sf;
    const int k0 = (c & 3) * 32;
    const bf16x8 a0 = *(const bf16x8*)(Abase + (long)r0 * NCH + k0 + koct);
    const bf16x8 a1 = *(const bf16x8*)(Abase + (long)r1 * NCH + k0 + koct);
    const unsigned short* bp = pack + ((long)(c * 8) * 64 + lane) * 8;
#pragma unroll
    for (int t = 0; t < 8; ++t) {
      const bf16x8 bfrag = *(const bf16x8*)(bp + (long)t * 512);
      acc[0][t] = __builtin_amdgcn_mfma_f32_16x16x32_bf16(a0, bfrag, acc[0][t], 0, 0, 0);
      acc[1][t] = __builtin_amdgcn_mfma_f32_16x16x32_bf16(a1, bfrag, acc[1][t], 0, 0, 0);
    }
  }

  // epilogue: C/D layout col=lane&15, row=(lane>>4)*4+reg
  const int nloc = lane & 15;
  const int rquad = (lane >> 4) * 4;
#pragma unroll
  for (int mt = 0; mt < 2; ++mt) {
#pragma unroll
    for (int t = 0; t < 8; ++t) {
      const int n = t * 16 + nloc;
      const float bias = bsum[n];
#pragma unroll
      for (int r = 0; r < 4; ++r) {
        const int m = R + mt * 16 + rquad + r;
        if (m < M && n < NO) {
          float v = acc[mt][t][r] + bias;
          if (do_relu) v = fmaxf(v, 0.f);
          if (outb) {
            outb[(long)m * NCH + n] = f2b(v);
            out8[(long)m * NCH + n] = f2q(v);
          } else {
            outf[(long)m * NO + n] = v;
          }
        }
      }
    }
  }
}

// ---------------- launch ----------------

extern "C" void kernel_launch(void* const* d_in, const int* in_sizes, int n_in,
                              void* d_out, int out_size, void* d_ws, size_t ws_size,
                              hipStream_t stream) {
  const float* x = (const float*)d_in[0];
  const int* ei = (const int*)d_in[1];
  const float* W1l = (const float*)d_in[2];
  const float* b1l = (const float*)d_in[3];
  const float* W1r = (const float*)d_in[4];
  const float* b1r = (const float*)d_in[5];
  const float* W2l = (const float*)d_in[6];
  const float* b2l = (const float*)d_in[7];
  const float* W2r = (const float*)d_in[8];
  const float* b2r = (const float*)d_in[9];
  float* out = (float*)d_out;

  const int N = in_sizes[0] / NCH;  // 40000
  const int E = in_sizes[1] / 2;    // 640000
  const int NOUT = out_size / N;    // 121

  const int* src = ei;
  const int* dst = ei + E;

  char* w = (char*)d_ws;
  auto alloc = [&](size_t bytes) {
    char* p = w;
    w += (bytes + 255) & ~(size_t)255;
    return p;
  };
  unsigned short* xb = (unsigned short*)alloc((size_t)N * NCH * 2);
  unsigned short* hb = (unsigned short*)alloc((size_t)N * NCH * 2);
  unsigned short* aggb = (unsigned short*)alloc((size_t)N * NCH * 2);
  unsigned char* x8 = (unsigned char*)alloc((size_t)N * NCH);
  unsigned char* h8 = (unsigned char*)alloc((size_t)N * NCH);
  unsigned short* pack1 = (unsigned short*)alloc(8 * 8 * 64 * 8 * 2);
  unsigned short* pack2 = (unsigned short*)alloc(8 * 8 * 64 * 8 * 2);
  float* bsum1 = (float*)alloc(128 * 4);
  float* bsum2 = (float*)alloc(128 * 4);
  int* cntx = (int*)alloc(((size_t)N * 8 + 4) * 4);  // [node][xcc] + ovf_n
  int* ovf_n = cntx + (size_t)N * 8;
  unsigned short* slotu = (unsigned short*)alloc((size_t)N * 128 * 2);
  int2* ovf = (int2*)alloc((size_t)E * 8);

  const int n4 = N * NCH / 4;
  const int nbBkt = (E + 256 * EPT - 1) / (256 * EPT);  // 313
  const int nbCvt = (n4 + 255) / 256;                   // 5000

  // zero per-XCD degree counters + overflow count
  hipMemsetAsync(cntx, 0, ((size_t)N * 8 + 4) * 4, stream);

  // bucket || convert || prepack in one dispatch
  k_main<<<nbBkt + nbCvt + 32, 256, 0, stream>>>(
      src, dst, E, cntx, slotu, ovf_n, ovf,
      x, xb, x8, n4,
      W1l, W1r, b1l, b1r, W2l, W2r, b2l, b2r,
      pack1, pack2, bsum1, bsum2, NOUT, nbBkt, nbCvt);

  const int gaggr = (N + 15) / 16;   // 2500 (16 nodes per 256-thread block)
  const int gblk = (N + 127) / 128;  // 313

  // layer 1 (relu, bf16 + fp8 out)
  k_agg<<<gaggr, 256, 0, stream>>>(x8, cntx, slotu, ovf_n, ovf, aggb, N);
  k_gemm<<<gblk, 256, 0, stream>>>(aggb, xb, pack1, bsum1, hb, h8,
                                   (float*)nullptr, N, NCH, 1);
  // layer 2 (f32 out)
  k_agg<<<gaggr, 256, 0, stream>>>(h8, cntx, slotu, ovf_n, ovf, aggb, N);
  k_gemm<<<gblk, 256, 0, stream>>>(aggb, hb, pack2, bsum2,
                                   (unsigned short*)nullptr, (unsigned char*)nullptr,
                                   out, N, NOUT, 0);
}